// Round 15
// baseline (146.528 us; speedup 1.0000x reference)
//
#include <hip/hip_runtime.h>
#include <math.h>

#define NJ 16
#define NV 778
#define M3 2334   // NV*3
#define S  16     // samples per block in k3a

typedef float f32x16 __attribute__((ext_vector_type(16)));

__device__ __forceinline__ f32x16 splat16(float x) {
    f32x16 r;
#pragma unroll
    for (int i = 0; i < 16; ++i) r[i] = x;
    return r;
}
// elementwise fused r = f*s + c (all constant indices -> pure SSA)
__device__ __forceinline__ f32x16 fma16v(f32x16 f, float s, f32x16 c) {
    f32x16 r;
    r[0]  = fmaf(f[0],  s, c[0]);  r[1]  = fmaf(f[1],  s, c[1]);
    r[2]  = fmaf(f[2],  s, c[2]);  r[3]  = fmaf(f[3],  s, c[3]);
    r[4]  = fmaf(f[4],  s, c[4]);  r[5]  = fmaf(f[5],  s, c[5]);
    r[6]  = fmaf(f[6],  s, c[6]);  r[7]  = fmaf(f[7],  s, c[7]);
    r[8]  = fmaf(f[8],  s, c[8]);  r[9]  = fmaf(f[9],  s, c[9]);
    r[10] = fmaf(f[10], s, c[10]); r[11] = fmaf(f[11], s, c[11]);
    r[12] = fmaf(f[12], s, c[12]); r[13] = fmaf(f[13], s, c[13]);
    r[14] = fmaf(f[14], s, c[14]); r[15] = fmaf(f[15], s, c[15]);
    return r;
}

// d_out layout (floats): verts [N*2334] | joints [N*48] | Rs [N*144]
// d_ws layout (floats):  A [N*192] | jpart [N*4*48]
// Pipeline: k0 -> k1 -> k2(A->ws) -> k3a(v_posed->verts, S=16, depth-2
//           prefetch) -> k4a(blend, A in LDS) -> k4b(joint partials) -> k5
//
// LAUNCH-BOUNDS LESSON (R4, R8): second arg w caps VGPR at 256/w -> only (B,1).
// LATENCY LESSONS (R9-R14): (a) per-sample multi-barrier blocks serialize;
// (b) dependent L2 load chains need LDS staging (k4a) or software prefetch
// (k3a depth-2): load->use distance must exceed ~200cy/waves_per_simd.

// ---------------- K0: SJ[b,j,c] = sum_v shapedirs[b,v,c]*Jreg[v,j]; b==10 -> vtemp
__global__ __launch_bounds__(64) void k0_prep(
    const float* __restrict__ shapedirs,
    const float* __restrict__ Jreg,
    const float* __restrict__ vtemp,
    float* __restrict__ SJJT)   // 528 floats
{
    int b = blockIdx.x / 16;    // 0..9 = shapedirs row, 10 = vtemp
    int j = blockIdx.x % 16;
    int t = threadIdx.x;
    const float* src = (b < 10) ? (shapedirs + (size_t)b * M3) : vtemp;
    float a0 = 0.f, a1 = 0.f, a2 = 0.f;
    for (int v = t; v < NV; v += 64) {
        float jr = Jreg[v * 16 + j];
        a0 = fmaf(src[v*3 + 0], jr, a0);
        a1 = fmaf(src[v*3 + 1], jr, a1);
        a2 = fmaf(src[v*3 + 2], jr, a2);
    }
#pragma unroll
    for (int m = 1; m < 64; m <<= 1) {
        a0 += __shfl_xor(a0, m);
        a1 += __shfl_xor(a1, m);
        a2 += __shfl_xor(a2, m);
    }
    if (t == 0) {
        int base = (b < 10) ? (b*48 + j*3) : (480 + j*3);
        SJJT[base + 0] = a0;
        SJJT[base + 1] = a1;
        SJJT[base + 2] = a2;
    }
}

// ---------------- K1: Rodrigues, one thread per (n, joint)
__global__ __launch_bounds__(256) void k1_rodrigues(
    const float* __restrict__ theta, float* __restrict__ RsOut, int N)
{
    int idx = blockIdx.x * 256 + threadIdx.x;
    if (idx >= N * NJ) return;
    int n = idx >> 4;
    int j = idx & 15;
    float t0 = theta[n*48 + j*3 + 0];
    float t1 = theta[n*48 + j*3 + 1];
    float t2 = theta[n*48 + j*3 + 2];
    const float eps = 1e-8f;
    float a0 = t0 + eps, a1 = t1 + eps, a2 = t2 + eps;
    float angle = sqrtf(a0*a0 + a1*a1 + a2*a2);
    float inv  = 1.0f / angle;
    float half = 0.5f * angle;
    float sh = sinf(half), chh = cosf(half);
    float qw = chh;
    float qx = sh * t0 * inv;
    float qy = sh * t1 * inv;
    float qz = sh * t2 * inv;
    float qn = 1.0f / sqrtf(qw*qw + qx*qx + qy*qy + qz*qz);
    qw *= qn; qx *= qn; qy *= qn; qz *= qn;
    float w2=qw*qw, x2=qx*qx, y2=qy*qy, z2=qz*qz;
    float wx=qw*qx, wy=qw*qy, wz=qw*qz;
    float xy=qx*qy, xz=qx*qz, yz=qy*qz;
    float* R = RsOut + (size_t)idx * 9;
    R[0] = w2 + x2 - y2 - z2;
    R[1] = 2.f*(xy - wz);
    R[2] = 2.f*(wy + xz);
    R[3] = 2.f*(wz + xy);
    R[4] = w2 - x2 + y2 - z2;
    R[5] = 2.f*(yz - wx);
    R[6] = 2.f*(xz - wy);
    R[7] = 2.f*(wx + yz);
    R[8] = w2 - x2 - y2 + z2;
}

// ---------------- K2: kinematic chain -> A into d_ws (192 floats / sample)
__global__ __launch_bounds__(64) void k2_chain(
    const float* __restrict__ beta,
    const float* __restrict__ Rs,     // d_out Rs region
    const float* __restrict__ SJJT,   // 528 floats
    float* __restrict__ Aws,          // d_ws; A[n] at n*192
    int N)
{
    __shared__ float sS[528];
    for (int i = threadIdx.x; i < 528; i += 64) sS[i] = SJJT[i];
    __syncthreads();
    int gid = blockIdx.x * 64 + threadIdx.x;
    if (gid >= N * 5) return;
    int n  = gid / 5;
    int ch = gid % 5;

    float b[10];
#pragma unroll
    for (int i = 0; i < 10; ++i) b[i] = beta[n*10 + i];

    int jidx[4];
    jidx[0] = 0; jidx[1] = ch*3 + 1; jidx[2] = ch*3 + 2; jidx[3] = ch*3 + 3;
    float J[4][3];
#pragma unroll
    for (int q = 0; q < 4; ++q) {
        int j = jidx[q];
#pragma unroll
        for (int c = 0; c < 3; ++c) {
            float acc = sS[480 + j*3 + c];
#pragma unroll
            for (int qq = 0; qq < 10; ++qq)
                acc = fmaf(b[qq], sS[qq*48 + j*3 + c], acc);
            J[q][c] = acc;
        }
    }

    const float* Rn = Rs + (size_t)n * 144;
    float* An = Aws + (size_t)n * 192;

    float GpR[9], Gpt[3];
#pragma unroll
    for (int r = 0; r < 3; ++r) {
        GpR[r*3+0] =  Rn[r*3+0];
        GpR[r*3+1] = -Rn[r*3+1];
        GpR[r*3+2] = -Rn[r*3+2];
    }
    Gpt[0] = J[0][0]; Gpt[1] = J[0][1]; Gpt[2] = J[0][2];

    if (ch == 0) {
#pragma unroll
        for (int r = 0; r < 3; ++r) {
            float rel = GpR[r*3+0]*J[0][0] + GpR[r*3+1]*J[0][1] + GpR[r*3+2]*J[0][2];
            An[r*4 + 0] = GpR[r*3+0];
            An[r*4 + 1] = GpR[r*3+1];
            An[r*4 + 2] = GpR[r*3+2];
            An[r*4 + 3] = Gpt[r] - rel;
        }
    }

#pragma unroll
    for (int st = 0; st < 3; ++st) {
        int i = jidx[st+1];
        const float* Ri = Rn + (size_t)i * 9;
        float t0 = J[st+1][0] - J[st][0];
        float t1 = J[st+1][1] - J[st][1];
        float t2 = J[st+1][2] - J[st][2];
        float GR[9], Gt[3];
#pragma unroll
        for (int r = 0; r < 3; ++r) {
#pragma unroll
            for (int c = 0; c < 3; ++c)
                GR[r*3+c] = GpR[r*3+0]*Ri[c] + GpR[r*3+1]*Ri[3+c] + GpR[r*3+2]*Ri[6+c];
            Gt[r] = GpR[r*3+0]*t0 + GpR[r*3+1]*t1 + GpR[r*3+2]*t2 + Gpt[r];
        }
#pragma unroll
        for (int r = 0; r < 3; ++r) {
            float rel = GR[r*3+0]*J[st+1][0] + GR[r*3+1]*J[st+1][1] + GR[r*3+2]*J[st+1][2];
            An[i*12 + r*4 + 0] = GR[r*3+0];
            An[i*12 + r*4 + 1] = GR[r*3+1];
            An[i*12 + r*4 + 2] = GR[r*3+2];
            An[i*12 + r*4 + 3] = Gt[r] - rel;
        }
#pragma unroll
        for (int r = 0; r < 9; ++r) GpR[r] = GR[r];
        Gpt[0] = Gt[0]; Gpt[1] = Gt[1]; Gpt[2] = Gt[2];
    }
}

// ---------------- K3a: GEMM. Block = 16 samples x 256-vert quarter; 1 vert/
// thread, acc = 3 f32x16 = 48 VGPR. posedirs loop software-pipelined depth 2:
// load row k+2 issued before FMAs of row k -> load->use distance ~192 FMA-issue
// cycles per wave (x4 waves/SIMD covers L2 ~200cy).
__global__ __launch_bounds__(256, 1) void k3a_gemm(
    const float* __restrict__ beta,
    const float* __restrict__ posedirs,
    const float* __restrict__ shapedirs,
    const float* __restrict__ vtemp,
    const float* __restrict__ Rs,
    float* __restrict__ vposed,         // verts region
    int N)
{
    __shared__ __attribute__((aligned(64))) float sF[145][S]; // 10 beta + 135 posefeat
    const int n0  = blockIdx.x * S;
    const int tid = threadIdx.x;

    // stage features: k<10 -> beta[k]; k>=10 -> Rs[9 + (k-10)] - I
    for (int idx = tid; idx < 145 * S; idx += 256) {
        int k = idx / S, s = idx % S;
        float val;
        if (k < 10) {
            val = beta[(size_t)(n0+s)*10 + k];
        } else {
            int kk = k - 10;
            int rr = kk % 9;
            val = Rs[(size_t)(n0+s)*144 + 9 + kk];
            if ((rr & 3) == 0) val -= 1.f;   // rr in {0,4,8}
        }
        sF[k][s] = val;
    }
    __syncthreads();

    const int v  = blockIdx.y * 256 + tid;      // 0..1023
    const int vc = (v < NV) ? v : (NV - 1);     // clamp: no divergence

    f32x16 ax = splat16(vtemp[vc*3+0]);
    f32x16 ay = splat16(vtemp[vc*3+1]);
    f32x16 az = splat16(vtemp[vc*3+2]);

    // shapedirs prologue (10 rows, unpipelined — small)
#pragma unroll
    for (int k = 0; k < 10; ++k) {
        const float* r_ = shapedirs + (size_t)k*M3 + 3*vc;
        float x_ = r_[0], y_ = r_[1], z_ = r_[2];
        f32x16 fv_ = *(const f32x16*)&sF[k][0];
        ax = fma16v(fv_, x_, ax);
        ay = fma16v(fv_, y_, ay);
        az = fma16v(fv_, z_, az);
    }

    // posedirs main loop: depth-2 software pipeline (branch-free clamped index)
    {
        const float* r0_ = posedirs + 3*vc;
        const float* r1_ = posedirs + (size_t)1*M3 + 3*vc;
        float x0 = r0_[0], y0 = r0_[1], z0 = r0_[2];
        float x1 = r1_[0], y1 = r1_[1], z1 = r1_[2];
#pragma unroll 5
        for (int k = 0; k < 135; ++k) {
            int kn = (k + 2 < 135) ? (k + 2) : 134;       // clamp, branch-free
            const float* rn_ = posedirs + (size_t)kn*M3 + 3*vc;
            float nx = rn_[0], ny = rn_[1], nz = rn_[2];  // issue load for k+2
            f32x16 fv_ = *(const f32x16*)&sF[k + 10][0];
            ax = fma16v(fv_, x0, ax);                      // consume row k
            ay = fma16v(fv_, y0, ay);
            az = fma16v(fv_, z0, az);
            x0 = x1; y0 = y1; z0 = z1;                     // rotate pipeline
            x1 = nx; y1 = ny; z1 = nz;
        }
    }

#pragma unroll
    for (int s = 0; s < S; ++s) {
        float* o = vposed + (size_t)(n0 + s)*M3 + (size_t)vc*3;
        o[0] = ax[s]; o[1] = ay[s]; o[2] = az[s];
    }
}

// ---------------- K4a: LBS blend, A staged in LDS. grid (N, 2); 2 verts/thread.
__global__ __launch_bounds__(256, 1) void k4a_blend(
    const float* __restrict__ Aws,      // d_ws
    const float* __restrict__ weights,
    float* verts,                       // in-place
    int N)
{
    __shared__ __attribute__((aligned(16))) float4 sA4[48];
    const int n   = blockIdx.x;
    const int q   = blockIdx.y;
    const int tid = threadIdx.x;

    if (tid < 48) sA4[tid] = reinterpret_cast<const float4*>(Aws + (size_t)n * 192)[tid];

    const int v0 = q * 512 + tid;               // always < 778
    const int v1 = v0 + 256;                    // q=1: 768..1023 -> guard
    const bool m1 = v1 < NV;
    const int c1 = m1 ? v1 : (NV - 1);

    float* vp0 = verts + (size_t)n * M3 + (size_t)v0 * 3;
    float* vp1 = verts + (size_t)n * M3 + (size_t)c1 * 3;
    float x0 = vp0[0], y0 = vp0[1], z0 = vp0[2];
    float x1 = vp1[0], y1 = vp1[1], z1 = vp1[2];
    f32x16 w0 = *reinterpret_cast<const f32x16*>(&weights[(size_t)v0 * 16]);
    f32x16 w1 = *reinterpret_cast<const f32x16*>(&weights[(size_t)c1 * 16]);

    __syncthreads();   // sA4 ready

    float o0x=0.f,o0y=0.f,o0z=0.f, o1x=0.f,o1y=0.f,o1z=0.f;

#define BJA2(j_) { \
    float4 A0 = sA4[(j_)*3+0], A1 = sA4[(j_)*3+1], A2 = sA4[(j_)*3+2]; \
    float X,Y,Z; \
    X = fmaf(A0.x,x0, fmaf(A0.y,y0, fmaf(A0.z,z0, A0.w))); \
    Y = fmaf(A1.x,x0, fmaf(A1.y,y0, fmaf(A1.z,z0, A1.w))); \
    Z = fmaf(A2.x,x0, fmaf(A2.y,y0, fmaf(A2.z,z0, A2.w))); \
    o0x = fmaf(w0[j_], X, o0x); o0y = fmaf(w0[j_], Y, o0y); o0z = fmaf(w0[j_], Z, o0z); \
    X = fmaf(A0.x,x1, fmaf(A0.y,y1, fmaf(A0.z,z1, A0.w))); \
    Y = fmaf(A1.x,x1, fmaf(A1.y,y1, fmaf(A1.z,z1, A1.w))); \
    Z = fmaf(A2.x,x1, fmaf(A2.y,y1, fmaf(A2.z,z1, A2.w))); \
    o1x = fmaf(w1[j_], X, o1x); o1y = fmaf(w1[j_], Y, o1y); o1z = fmaf(w1[j_], Z, o1z); }

    BJA2(0)  BJA2(1)  BJA2(2)  BJA2(3)  BJA2(4)  BJA2(5)  BJA2(6)  BJA2(7)
    BJA2(8)  BJA2(9)  BJA2(10) BJA2(11) BJA2(12) BJA2(13) BJA2(14) BJA2(15)
#undef BJA2

    vp0[0] = o0x; vp0[1] = o0y; vp0[2] = o0z;
    if (m1) { vp1[0] = o1x; vp1[1] = o1y; vp1[2] = o1z; }
}

// ---------------- K4b: joint partials, barrier-free. One thread per
// (n, chunk, j), j fastest (coalesced Jreg; verts broadcast across j-lanes).
__global__ __launch_bounds__(256, 1) void k4b_joints(
    const float* __restrict__ verts,
    const float* __restrict__ Jreg,
    float* __restrict__ jpart,          // d_ws + N*192
    int N)
{
    int gid = blockIdx.x * 256 + threadIdx.x;   // total N*4*16
    if (gid >= N * 64) return;
    int j  = gid & 15;
    int c4 = (gid >> 4) & 3;
    int n  = gid >> 6;

    int vbeg = c4 * 195;
    int vend = vbeg + 195; if (vend > NV) vend = NV;

    const float* vp = verts + (size_t)n * M3;
    float a0 = 0.f, a1 = 0.f, a2 = 0.f;
#pragma unroll 4
    for (int v = vbeg; v < vend; ++v) {
        float jr = Jreg[(size_t)v * 16 + j];
        float x = vp[v*3 + 0], y = vp[v*3 + 1], z = vp[v*3 + 2];
        a0 = fmaf(jr, x, a0);
        a1 = fmaf(jr, y, a1);
        a2 = fmaf(jr, z, a2);
    }
    float* o = jpart + (size_t)n * 192 + c4 * 48 + j * 3;
    o[0] = a0; o[1] = a1; o[2] = a2;
}

// ---------------- K5: joints[n*48+r] = sum_c4 jpart[n*192 + c4*48 + r]
__global__ __launch_bounds__(256) void k5_joint_sum(
    const float* __restrict__ jpart, float* __restrict__ joints, int N)
{
    int i = blockIdx.x * 256 + threadIdx.x;     // N*48
    if (i >= N * 48) return;
    int n = i / 48;
    int r = i - n * 48;
    const float* p = jpart + (size_t)n * 192 + r;
    joints[i] = p[0] + p[48] + p[96] + p[144];
}

extern "C" void kernel_launch(void* const* d_in, const int* in_sizes, int n_in,
                              void* d_out, int out_size, void* d_ws, size_t ws_size,
                              hipStream_t stream)
{
    const float* beta   = (const float*)d_in[0];
    const float* theta  = (const float*)d_in[1];
    const float* vtemp  = (const float*)d_in[2];
    const float* shaped = (const float*)d_in[3];
    const float* Jreg   = (const float*)d_in[4];
    const float* posed  = (const float*)d_in[5];
    const float* wts    = (const float*)d_in[6];
    float* out = (float*)d_out;
    const int N = in_sizes[0] / 10;   // 4096

    float* verts  = out;                            // N*2334
    float* joints = out + (size_t)N * M3;           // N*48
    float* RsOut  = joints + (size_t)N * 48;        // N*144
    float* Aws    = (float*)d_ws;                   // N*192 floats = 3.1 MB
    float* jpart  = Aws + (size_t)N * 192;          // N*192 floats = 3.1 MB

    k0_prep<<<176, 64, 0, stream>>>(shaped, Jreg, vtemp, joints);
    k1_rodrigues<<<(N*NJ + 255)/256, 256, 0, stream>>>(theta, RsOut, N);
    k2_chain<<<(N*5 + 63)/64, 64, 0, stream>>>(beta, RsOut, joints, Aws, N);
    k3a_gemm<<<dim3(N/S, 4), 256, 0, stream>>>(beta, posed, shaped, vtemp, RsOut, verts, N);
    k4a_blend<<<dim3(N, 2), 256, 0, stream>>>(Aws, wts, verts, N);
    k4b_joints<<<(N*64 + 255)/256, 256, 0, stream>>>(verts, Jreg, jpart, N);
    k5_joint_sum<<<(N*48 + 255)/256, 256, 0, stream>>>(jpart, joints, N);
}

// Round 16
// 137.933 us; speedup vs baseline: 1.0623x; 1.0623x over previous
//
#include <hip/hip_runtime.h>
#include <math.h>

#define NJ 16
#define NV 778
#define M3 2334   // NV*3
#define S  16     // samples per block in k3a

typedef float f32x16 __attribute__((ext_vector_type(16)));

__device__ __forceinline__ f32x16 splat16(float x) {
    f32x16 r;
#pragma unroll
    for (int i = 0; i < 16; ++i) r[i] = x;
    return r;
}

// d_out layout (floats): verts [N*2334] | joints [N*48] | Rs [N*144]
// d_ws layout (floats):  A [N*192] | Fg/jpart [N*192] (time-shared: k2b writes
//   Fg (2.32 MB), k3a reads it, then k4b overwrites the region as jpart)
// Pipeline: k0 -> k1 -> k2(A->ws) -> k2b(F->ws) -> k3a(v_posed->verts, features
//   via SGPR s_load) -> k4a(blend, A in LDS) -> k4b(joint partials) -> k5
//
// LAUNCH-BOUNDS LESSON (R4, R8): second arg w caps VGPR at 256/w -> only (B,1).
// LATENCY LESSONS (R9-R15): (a) per-sample multi-barrier blocks serialize;
// (b) dependent L2 chains need LDS staging (k4a); (c) wave-uniform data read
// per-iteration through LDS (4x ds_read_b128 x 16 waves/CU) serializes on the
// per-CU LDS unit -- route uniform operands through the SCALAR pipe (s_load +
// SGPR-operand v_fmac) instead.

// ---------------- K0: SJ[b,j,c] = sum_v shapedirs[b,v,c]*Jreg[v,j]; b==10 -> vtemp
__global__ __launch_bounds__(64) void k0_prep(
    const float* __restrict__ shapedirs,
    const float* __restrict__ Jreg,
    const float* __restrict__ vtemp,
    float* __restrict__ SJJT)   // 528 floats
{
    int b = blockIdx.x / 16;    // 0..9 = shapedirs row, 10 = vtemp
    int j = blockIdx.x % 16;
    int t = threadIdx.x;
    const float* src = (b < 10) ? (shapedirs + (size_t)b * M3) : vtemp;
    float a0 = 0.f, a1 = 0.f, a2 = 0.f;
    for (int v = t; v < NV; v += 64) {
        float jr = Jreg[v * 16 + j];
        a0 = fmaf(src[v*3 + 0], jr, a0);
        a1 = fmaf(src[v*3 + 1], jr, a1);
        a2 = fmaf(src[v*3 + 2], jr, a2);
    }
#pragma unroll
    for (int m = 1; m < 64; m <<= 1) {
        a0 += __shfl_xor(a0, m);
        a1 += __shfl_xor(a1, m);
        a2 += __shfl_xor(a2, m);
    }
    if (t == 0) {
        int base = (b < 10) ? (b*48 + j*3) : (480 + j*3);
        SJJT[base + 0] = a0;
        SJJT[base + 1] = a1;
        SJJT[base + 2] = a2;
    }
}

// ---------------- K1: Rodrigues, one thread per (n, joint)
__global__ __launch_bounds__(256) void k1_rodrigues(
    const float* __restrict__ theta, float* __restrict__ RsOut, int N)
{
    int idx = blockIdx.x * 256 + threadIdx.x;
    if (idx >= N * NJ) return;
    int n = idx >> 4;
    int j = idx & 15;
    float t0 = theta[n*48 + j*3 + 0];
    float t1 = theta[n*48 + j*3 + 1];
    float t2 = theta[n*48 + j*3 + 2];
    const float eps = 1e-8f;
    float a0 = t0 + eps, a1 = t1 + eps, a2 = t2 + eps;
    float angle = sqrtf(a0*a0 + a1*a1 + a2*a2);
    float inv  = 1.0f / angle;
    float half = 0.5f * angle;
    float sh = sinf(half), chh = cosf(half);
    float qw = chh;
    float qx = sh * t0 * inv;
    float qy = sh * t1 * inv;
    float qz = sh * t2 * inv;
    float qn = 1.0f / sqrtf(qw*qw + qx*qx + qy*qy + qz*qz);
    qw *= qn; qx *= qn; qy *= qn; qz *= qn;
    float w2=qw*qw, x2=qx*qx, y2=qy*qy, z2=qz*qz;
    float wx=qw*qx, wy=qw*qy, wz=qw*qz;
    float xy=qx*qy, xz=qx*qz, yz=qy*qz;
    float* R = RsOut + (size_t)idx * 9;
    R[0] = w2 + x2 - y2 - z2;
    R[1] = 2.f*(xy - wz);
    R[2] = 2.f*(wy + xz);
    R[3] = 2.f*(wz + xy);
    R[4] = w2 - x2 + y2 - z2;
    R[5] = 2.f*(yz - wx);
    R[6] = 2.f*(xz - wy);
    R[7] = 2.f*(wx + yz);
    R[8] = w2 - x2 - y2 + z2;
}

// ---------------- K2: kinematic chain -> A into d_ws (192 floats / sample)
__global__ __launch_bounds__(64) void k2_chain(
    const float* __restrict__ beta,
    const float* __restrict__ Rs,     // d_out Rs region
    const float* __restrict__ SJJT,   // 528 floats
    float* __restrict__ Aws,          // d_ws; A[n] at n*192
    int N)
{
    __shared__ float sS[528];
    for (int i = threadIdx.x; i < 528; i += 64) sS[i] = SJJT[i];
    __syncthreads();
    int gid = blockIdx.x * 64 + threadIdx.x;
    if (gid >= N * 5) return;
    int n  = gid / 5;
    int ch = gid % 5;

    float b[10];
#pragma unroll
    for (int i = 0; i < 10; ++i) b[i] = beta[n*10 + i];

    int jidx[4];
    jidx[0] = 0; jidx[1] = ch*3 + 1; jidx[2] = ch*3 + 2; jidx[3] = ch*3 + 3;
    float J[4][3];
#pragma unroll
    for (int q = 0; q < 4; ++q) {
        int j = jidx[q];
#pragma unroll
        for (int c = 0; c < 3; ++c) {
            float acc = sS[480 + j*3 + c];
#pragma unroll
            for (int qq = 0; qq < 10; ++qq)
                acc = fmaf(b[qq], sS[qq*48 + j*3 + c], acc);
            J[q][c] = acc;
        }
    }

    const float* Rn = Rs + (size_t)n * 144;
    float* An = Aws + (size_t)n * 192;

    float GpR[9], Gpt[3];
#pragma unroll
    for (int r = 0; r < 3; ++r) {
        GpR[r*3+0] =  Rn[r*3+0];
        GpR[r*3+1] = -Rn[r*3+1];
        GpR[r*3+2] = -Rn[r*3+2];
    }
    Gpt[0] = J[0][0]; Gpt[1] = J[0][1]; Gpt[2] = J[0][2];

    if (ch == 0) {
#pragma unroll
        for (int r = 0; r < 3; ++r) {
            float rel = GpR[r*3+0]*J[0][0] + GpR[r*3+1]*J[0][1] + GpR[r*3+2]*J[0][2];
            An[r*4 + 0] = GpR[r*3+0];
            An[r*4 + 1] = GpR[r*3+1];
            An[r*4 + 2] = GpR[r*3+2];
            An[r*4 + 3] = Gpt[r] - rel;
        }
    }

#pragma unroll
    for (int st = 0; st < 3; ++st) {
        int i = jidx[st+1];
        const float* Ri = Rn + (size_t)i * 9;
        float t0 = J[st+1][0] - J[st][0];
        float t1 = J[st+1][1] - J[st][1];
        float t2 = J[st+1][2] - J[st][2];
        float GR[9], Gt[3];
#pragma unroll
        for (int r = 0; r < 3; ++r) {
#pragma unroll
            for (int c = 0; c < 3; ++c)
                GR[r*3+c] = GpR[r*3+0]*Ri[c] + GpR[r*3+1]*Ri[3+c] + GpR[r*3+2]*Ri[6+c];
            Gt[r] = GpR[r*3+0]*t0 + GpR[r*3+1]*t1 + GpR[r*3+2]*t2 + Gpt[r];
        }
#pragma unroll
        for (int r = 0; r < 3; ++r) {
            float rel = GR[r*3+0]*J[st+1][0] + GR[r*3+1]*J[st+1][1] + GR[r*3+2]*J[st+1][2];
            An[i*12 + r*4 + 0] = GR[r*3+0];
            An[i*12 + r*4 + 1] = GR[r*3+1];
            An[i*12 + r*4 + 2] = GR[r*3+2];
            An[i*12 + r*4 + 3] = Gt[r] - rel;
        }
#pragma unroll
        for (int r = 0; r < 9; ++r) GpR[r] = GR[r];
        Gpt[0] = Gt[0]; Gpt[1] = Gt[1]; Gpt[2] = Gt[2];
    }
}

// ---------------- K2b: features -> global Fg[g][k][16] (g = sample group of 16)
// k<10: beta[n][k]; k>=10: Rs[n][9+(k-10)] - I. One thread per output float.
__global__ __launch_bounds__(256) void k2b_feat(
    const float* __restrict__ beta,
    const float* __restrict__ Rs,
    float* __restrict__ Fg,             // [N/16][145][16]
    int N)
{
    int idx = blockIdx.x * 256 + threadIdx.x;   // total (N/16)*145*16
    int total = (N / 16) * 145 * 16;
    if (idx >= total) return;
    int s = idx & 15;
    int k = (idx >> 4) % 145;
    int g = idx / (145 * 16);
    int n = g * 16 + s;
    float val;
    if (k < 10) {
        val = beta[(size_t)n * 10 + k];
    } else {
        int kk = k - 10;
        int rr = kk % 9;
        val = Rs[(size_t)n * 144 + 9 + kk];
        if ((rr & 3) == 0) val -= 1.f;          // rr in {0,4,8}
    }
    Fg[idx] = val;
}

// ---------------- K3a: GEMM, features via SCALAR pipe. Block = 16 samples x
// 256-vert quarter; 1 vert/thread, acc = 3 f32x16 = 48 VGPR. Per row: 16
// uniform feature floats (s_load into SGPRs) x per-lane (x,y,z) -> 48 v_fmac
// with SGPR multiplier. No LDS, no barrier.
#define FROW(FP, X_, Y_, Z_) { \
    float F0=(FP)[0], F1=(FP)[1], F2=(FP)[2],  F3=(FP)[3]; \
    float F4=(FP)[4], F5=(FP)[5], F6=(FP)[6],  F7=(FP)[7]; \
    float F8=(FP)[8], F9=(FP)[9], F10=(FP)[10],F11=(FP)[11]; \
    float F12=(FP)[12],F13=(FP)[13],F14=(FP)[14],F15=(FP)[15]; \
    ax[0]=fmaf(F0,X_,ax[0]);   ay[0]=fmaf(F0,Y_,ay[0]);   az[0]=fmaf(F0,Z_,az[0]); \
    ax[1]=fmaf(F1,X_,ax[1]);   ay[1]=fmaf(F1,Y_,ay[1]);   az[1]=fmaf(F1,Z_,az[1]); \
    ax[2]=fmaf(F2,X_,ax[2]);   ay[2]=fmaf(F2,Y_,ay[2]);   az[2]=fmaf(F2,Z_,az[2]); \
    ax[3]=fmaf(F3,X_,ax[3]);   ay[3]=fmaf(F3,Y_,ay[3]);   az[3]=fmaf(F3,Z_,az[3]); \
    ax[4]=fmaf(F4,X_,ax[4]);   ay[4]=fmaf(F4,Y_,ay[4]);   az[4]=fmaf(F4,Z_,az[4]); \
    ax[5]=fmaf(F5,X_,ax[5]);   ay[5]=fmaf(F5,Y_,ay[5]);   az[5]=fmaf(F5,Z_,az[5]); \
    ax[6]=fmaf(F6,X_,ax[6]);   ay[6]=fmaf(F6,Y_,ay[6]);   az[6]=fmaf(F6,Z_,az[6]); \
    ax[7]=fmaf(F7,X_,ax[7]);   ay[7]=fmaf(F7,Y_,ay[7]);   az[7]=fmaf(F7,Z_,az[7]); \
    ax[8]=fmaf(F8,X_,ax[8]);   ay[8]=fmaf(F8,Y_,ay[8]);   az[8]=fmaf(F8,Z_,az[8]); \
    ax[9]=fmaf(F9,X_,ax[9]);   ay[9]=fmaf(F9,Y_,ay[9]);   az[9]=fmaf(F9,Z_,az[9]); \
    ax[10]=fmaf(F10,X_,ax[10]);ay[10]=fmaf(F10,Y_,ay[10]);az[10]=fmaf(F10,Z_,az[10]); \
    ax[11]=fmaf(F11,X_,ax[11]);ay[11]=fmaf(F11,Y_,ay[11]);az[11]=fmaf(F11,Z_,az[11]); \
    ax[12]=fmaf(F12,X_,ax[12]);ay[12]=fmaf(F12,Y_,ay[12]);az[12]=fmaf(F12,Z_,az[12]); \
    ax[13]=fmaf(F13,X_,ax[13]);ay[13]=fmaf(F13,Y_,ay[13]);az[13]=fmaf(F13,Z_,az[13]); \
    ax[14]=fmaf(F14,X_,ax[14]);ay[14]=fmaf(F14,Y_,ay[14]);az[14]=fmaf(F14,Z_,az[14]); \
    ax[15]=fmaf(F15,X_,ax[15]);ay[15]=fmaf(F15,Y_,ay[15]);az[15]=fmaf(F15,Z_,az[15]); }

__global__ __launch_bounds__(256, 1) void k3a_gemm(
    const float* __restrict__ Fg,       // [N/16][145][16] (ws, from k2b)
    const float* __restrict__ posedirs,
    const float* __restrict__ shapedirs,
    const float* __restrict__ vtemp,
    float* __restrict__ vposed,         // verts region
    int N)
{
    const int g   = blockIdx.x;                 // sample group
    const int n0  = g * S;
    const int tid = threadIdx.x;
    const int v   = blockIdx.y * 256 + tid;     // 0..1023
    const int vc  = (v < NV) ? v : (NV - 1);    // clamp: no divergence

    const float* F = Fg + (size_t)g * 145 * 16; // uniform base

    f32x16 ax = splat16(vtemp[vc*3+0]);
    f32x16 ay = splat16(vtemp[vc*3+1]);
    f32x16 az = splat16(vtemp[vc*3+2]);

    // shapedirs rows 0..9
#pragma unroll
    for (int k = 0; k < 10; ++k) {
        const float* r_ = shapedirs + (size_t)k*M3 + 3*vc;
        float x_ = r_[0], y_ = r_[1], z_ = r_[2];
        FROW(F + k*16, x_, y_, z_)
    }

    // posedirs rows 10..144, depth-2 prefetch on the per-lane vector load
    {
        const float* r0_ = posedirs + 3*vc;
        const float* r1_ = posedirs + (size_t)1*M3 + 3*vc;
        float x0 = r0_[0], y0 = r0_[1], z0 = r0_[2];
        float x1 = r1_[0], y1 = r1_[1], z1 = r1_[2];
        for (int k = 0; k < 135; ++k) {
            int kn = (k + 2 < 135) ? (k + 2) : 134;
            const float* rn_ = posedirs + (size_t)kn*M3 + 3*vc;
            float nx = rn_[0], ny = rn_[1], nz = rn_[2];
            FROW(F + (k + 10)*16, x0, y0, z0)
            x0 = x1; y0 = y1; z0 = z1;
            x1 = nx; y1 = ny; z1 = nz;
        }
    }

#pragma unroll
    for (int s = 0; s < S; ++s) {
        float* o = vposed + (size_t)(n0 + s)*M3 + (size_t)vc*3;
        o[0] = ax[s]; o[1] = ay[s]; o[2] = az[s];
    }
}

// ---------------- K4a: LBS blend, A staged in LDS. grid (N, 2); 2 verts/thread.
__global__ __launch_bounds__(256, 1) void k4a_blend(
    const float* __restrict__ Aws,      // d_ws
    const float* __restrict__ weights,
    float* verts,                       // in-place
    int N)
{
    typedef float f32x16v __attribute__((ext_vector_type(16)));
    __shared__ __attribute__((aligned(16))) float4 sA4[48];
    const int n   = blockIdx.x;
    const int q   = blockIdx.y;
    const int tid = threadIdx.x;

    if (tid < 48) sA4[tid] = reinterpret_cast<const float4*>(Aws + (size_t)n * 192)[tid];

    const int v0 = q * 512 + tid;               // always < 778
    const int v1 = v0 + 256;                    // q=1: 768..1023 -> guard
    const bool m1 = v1 < NV;
    const int c1 = m1 ? v1 : (NV - 1);

    float* vp0 = verts + (size_t)n * M3 + (size_t)v0 * 3;
    float* vp1 = verts + (size_t)n * M3 + (size_t)c1 * 3;
    float x0 = vp0[0], y0 = vp0[1], z0 = vp0[2];
    float x1 = vp1[0], y1 = vp1[1], z1 = vp1[2];
    f32x16v w0 = *reinterpret_cast<const f32x16v*>(&weights[(size_t)v0 * 16]);
    f32x16v w1 = *reinterpret_cast<const f32x16v*>(&weights[(size_t)c1 * 16]);

    __syncthreads();   // sA4 ready

    float o0x=0.f,o0y=0.f,o0z=0.f, o1x=0.f,o1y=0.f,o1z=0.f;

#define BJA2(j_) { \
    float4 A0 = sA4[(j_)*3+0], A1 = sA4[(j_)*3+1], A2 = sA4[(j_)*3+2]; \
    float X,Y,Z; \
    X = fmaf(A0.x,x0, fmaf(A0.y,y0, fmaf(A0.z,z0, A0.w))); \
    Y = fmaf(A1.x,x0, fmaf(A1.y,y0, fmaf(A1.z,z0, A1.w))); \
    Z = fmaf(A2.x,x0, fmaf(A2.y,y0, fmaf(A2.z,z0, A2.w))); \
    o0x = fmaf(w0[j_], X, o0x); o0y = fmaf(w0[j_], Y, o0y); o0z = fmaf(w0[j_], Z, o0z); \
    X = fmaf(A0.x,x1, fmaf(A0.y,y1, fmaf(A0.z,z1, A0.w))); \
    Y = fmaf(A1.x,x1, fmaf(A1.y,y1, fmaf(A1.z,z1, A1.w))); \
    Z = fmaf(A2.x,x1, fmaf(A2.y,y1, fmaf(A2.z,z1, A2.w))); \
    o1x = fmaf(w1[j_], X, o1x); o1y = fmaf(w1[j_], Y, o1y); o1z = fmaf(w1[j_], Z, o1z); }

    BJA2(0)  BJA2(1)  BJA2(2)  BJA2(3)  BJA2(4)  BJA2(5)  BJA2(6)  BJA2(7)
    BJA2(8)  BJA2(9)  BJA2(10) BJA2(11) BJA2(12) BJA2(13) BJA2(14) BJA2(15)
#undef BJA2

    vp0[0] = o0x; vp0[1] = o0y; vp0[2] = o0z;
    if (m1) { vp1[0] = o1x; vp1[1] = o1y; vp1[2] = o1z; }
}

// ---------------- K4b: joint partials, barrier-free. One thread per
// (n, chunk, j), j fastest (coalesced Jreg; verts broadcast across j-lanes).
__global__ __launch_bounds__(256, 1) void k4b_joints(
    const float* __restrict__ verts,
    const float* __restrict__ Jreg,
    float* __restrict__ jpart,          // d_ws + N*192 (overwrites Fg)
    int N)
{
    int gid = blockIdx.x * 256 + threadIdx.x;   // total N*4*16
    if (gid >= N * 64) return;
    int j  = gid & 15;
    int c4 = (gid >> 4) & 3;
    int n  = gid >> 6;

    int vbeg = c4 * 195;
    int vend = vbeg + 195; if (vend > NV) vend = NV;

    const float* vp = verts + (size_t)n * M3;
    float a0 = 0.f, a1 = 0.f, a2 = 0.f;
#pragma unroll 4
    for (int v = vbeg; v < vend; ++v) {
        float jr = Jreg[(size_t)v * 16 + j];
        float x = vp[v*3 + 0], y = vp[v*3 + 1], z = vp[v*3 + 2];
        a0 = fmaf(jr, x, a0);
        a1 = fmaf(jr, y, a1);
        a2 = fmaf(jr, z, a2);
    }
    float* o = jpart + (size_t)n * 192 + c4 * 48 + j * 3;
    o[0] = a0; o[1] = a1; o[2] = a2;
}

// ---------------- K5: joints[n*48+r] = sum_c4 jpart[n*192 + c4*48 + r]
__global__ __launch_bounds__(256) void k5_joint_sum(
    const float* __restrict__ jpart, float* __restrict__ joints, int N)
{
    int i = blockIdx.x * 256 + threadIdx.x;     // N*48
    if (i >= N * 48) return;
    int n = i / 48;
    int r = i - n * 48;
    const float* p = jpart + (size_t)n * 192 + r;
    joints[i] = p[0] + p[48] + p[96] + p[144];
}

extern "C" void kernel_launch(void* const* d_in, const int* in_sizes, int n_in,
                              void* d_out, int out_size, void* d_ws, size_t ws_size,
                              hipStream_t stream)
{
    const float* beta   = (const float*)d_in[0];
    const float* theta  = (const float*)d_in[1];
    const float* vtemp  = (const float*)d_in[2];
    const float* shaped = (const float*)d_in[3];
    const float* Jreg   = (const float*)d_in[4];
    const float* posed  = (const float*)d_in[5];
    const float* wts    = (const float*)d_in[6];
    float* out = (float*)d_out;
    const int N = in_sizes[0] / 10;   // 4096

    float* verts  = out;                            // N*2334
    float* joints = out + (size_t)N * M3;           // N*48
    float* RsOut  = joints + (size_t)N * 48;        // N*144
    float* Aws    = (float*)d_ws;                   // N*192 floats = 3.1 MB
    float* Fg     = Aws + (size_t)N * 192;          // 2.32 MB (then jpart)
    float* jpart  = Fg;                             // k4b overwrites after k3a

    const int nF = (N / 16) * 145 * 16;

    k0_prep<<<176, 64, 0, stream>>>(shaped, Jreg, vtemp, joints);
    k1_rodrigues<<<(N*NJ + 255)/256, 256, 0, stream>>>(theta, RsOut, N);
    k2_chain<<<(N*5 + 63)/64, 64, 0, stream>>>(beta, RsOut, joints, Aws, N);
    k2b_feat<<<(nF + 255)/256, 256, 0, stream>>>(beta, RsOut, Fg, N);
    k3a_gemm<<<dim3(N/S, 4), 256, 0, stream>>>(Fg, posed, shaped, vtemp, verts, N);
    k4a_blend<<<dim3(N, 2), 256, 0, stream>>>(Aws, wts, verts, N);
    k4b_joints<<<(N*64 + 255)/256, 256, 0, stream>>>(verts, Jreg, jpart, N);
    k5_joint_sum<<<(N*48 + 255)/256, 256, 0, stream>>>(jpart, joints, N);
}